// Round 1
// baseline (887.184 us; speedup 1.0000x reference)
//
#include <hip/hip_runtime.h>
#include <cstdint>
#include <cstddef>

namespace {

constexpr float BNS = 0.99999500003749973f; // 1/sqrt(1+1e-5)

constexpr int TB = 32;      // T*B
constexpr int C  = 384;
constexpr int N  = 256;     // H*W
constexpr int ED = 96;
constexpr int ROWS = 868;   // 96 k + 384 v + 4 router + 384 q(E*ed)
constexpr int HID = 2048;
constexpr int HH  = 1024;

// workspace offsets (in floats)
constexpr size_t O_WPACK = 0;                       // 868*384
constexpr size_t O_A1S = 333312;                    // 868
constexpr size_t O_A1B = O_A1S + 868;               // 868
constexpr size_t O_APS = O_A1B + 868;               // 384
constexpr size_t O_APB = O_APS + 384;
constexpr size_t O_AHS = O_APB + 384;               // 2048
constexpr size_t O_AHB = O_AHS + 2048;
constexpr size_t O_ADS = O_AHB + 2048;              // 1024
constexpr size_t O_ADB = O_ADS + 1024;
constexpr size_t O_AFS = O_ADB + 1024;              // 384
constexpr size_t O_AFB = O_AFS + 384;
constexpr size_t O_PRE = 342784;                    // TB*ROWS*N = 7110656 (in-place LIF)
constexpr size_t O_BIG = O_PRE + (size_t)TB * ROWS * N;          // 7453440
// phase A
constexpr size_t O_ATTN = O_BIG;                                  // 4*32*256*256 = 8388608
constexpr size_t O_RES  = O_BIG + 8388608;                        // 4*32*256*384 = 12582912
constexpr size_t O_Y    = O_RES + 12582912;                       // 32*384*256 = 3145728
constexpr size_t O_PP   = O_Y + 3145728;                          // 3145728
// phase B (overwrites phase A)
constexpr size_t O_H    = O_BIG;                                  // 32*2048*256 = 16777216
constexpr size_t O_M    = O_BIG + 16777216;                       // 32*1024*256 = 8388608
constexpr size_t O_F2   = O_PRE;                                  // 3145728 (PRE dead by then)

// ---------------- pack weights + affines ----------------
__global__ __launch_bounds__(256) void pack_kernel(
    const float* __restrict__ kw, const float* __restrict__ vw,
    const float* __restrict__ rw, const float* __restrict__ rb,
    const float* __restrict__ rg, const float* __restrict__ rbe,
    const float* __restrict__ ew, const float* __restrict__ eg,
    const float* __restrict__ eb,
    float* __restrict__ WP, float* __restrict__ a1s, float* __restrict__ a1b)
{
  int u = blockIdx.x * 256 + threadIdx.x;
  if (u < ROWS * C) {
    int r = u / C, d = u % C;
    float w;
    if (r < 96)       w = kw[r * C + d];
    else if (r < 480) w = vw[(r - 96) * C + d];
    else if (r < 484) w = rw[(r - 480) * C + d];
    else              w = ew[(r - 484) * C + d];
    WP[u] = w;
  }
  if (u < ROWS) {
    float s, b;
    if (u < 480)      { s = 1.0f; b = 0.0f; }
    else if (u < 484) { int e = u - 480; s = rg[e] * BNS; b = rb[e] * rg[e] * BNS + rbe[e]; }
    else              { int j = u - 484; s = eg[j] * BNS; b = eb[j]; }
    a1s[u] = s; a1b[u] = b;
  }
}

__global__ __launch_bounds__(256) void aff_kernel(
    const float* __restrict__ g, const float* __restrict__ bias,
    const float* __restrict__ be, float* __restrict__ s, float* __restrict__ b, int n)
{
  int u = blockIdx.x * 256 + threadIdx.x;
  if (u < n) { s[u] = g[u] * BNS; b[u] = bias[u] * g[u] * BNS + be[u]; }
}

// ---------------- generic GEMM: OUT[b,o,n] = (sum_d W[o,d]*X[b,d,n])*s[o]+b[o] ----------------
__global__ __launch_bounds__(256) void gemm_wx(
    const float* __restrict__ W, const float* __restrict__ X, float* __restrict__ OUT,
    const float* __restrict__ aS, const float* __restrict__ aB,
    int O, int D, long xStride, long oStride)
{
  __shared__ float Wt[16][65];
  __shared__ float Xt[16][64];
  const float* Xb = X + (size_t)blockIdx.z * xStride;
  float* Ob = OUT + (size_t)blockIdx.z * oStride;
  int n0 = blockIdx.x * 64, o0 = blockIdx.y * 64;
  int t = threadIdx.x, tx = t & 15, ty = t >> 4;
  float acc[4][4] = {};
  for (int kt = 0; kt < D; kt += 16) {
#pragma unroll
    for (int l = 0; l < 4; ++l) {
      int idx = t + l * 256;
      int r = idx >> 4, c = idx & 15;
      int orow = o0 + r;
      Wt[c][r] = (orow < O) ? W[(size_t)orow * D + kt + c] : 0.0f;
      int r2 = idx >> 6, c2 = idx & 63;
      Xt[r2][c2] = Xb[(size_t)(kt + r2) * N + n0 + c2];
    }
    __syncthreads();
#pragma unroll
    for (int k = 0; k < 16; ++k) {
      float a[4], b[4];
#pragma unroll
      for (int i = 0; i < 4; ++i) a[i] = Wt[k][ty * 4 + i];
#pragma unroll
      for (int j = 0; j < 4; ++j) b[j] = Xt[k][tx * 4 + j];
#pragma unroll
      for (int i = 0; i < 4; ++i)
#pragma unroll
        for (int j = 0; j < 4; ++j) acc[i][j] += a[i] * b[j];
    }
    __syncthreads();
  }
#pragma unroll
  for (int i = 0; i < 4; ++i) {
    int orow = o0 + ty * 4 + i;
    if (orow < O) {
      float s = aS[orow], b = aB[orow];
#pragma unroll
      for (int j = 0; j < 4; ++j)
        Ob[(size_t)orow * N + n0 + tx * 4 + j] = acc[i][j] * s + b;
    }
  }
}

// ---------------- LIF (in place): p shape (nOuter, TB, FN); tb = t*8+b ----------------
__global__ __launch_bounds__(256) void lif_kernel(float* __restrict__ p, int FN)
{
  int j = blockIdx.x * 256 + threadIdx.x;
  int yb = blockIdx.y; int b = yb & 7; int e = yb >> 3;
  float mem = 0.0f;
#pragma unroll
  for (int t = 0; t < 4; ++t) {
    size_t idx = (size_t)(e * 32 + t * 8 + b) * FN + j;
    float x = p[idx];
    mem += (x - mem) * 0.5f;
    float sp = (mem >= 1.0f) ? 1.0f : 0.0f;
    p[idx] = sp;
    mem = (sp != 0.0f) ? 0.0f : mem;
  }
}

// ---------------- attn[e,tb,n,m] = sum_c q[c,n]*k[c,m] ----------------
__global__ __launch_bounds__(256) void attn_kernel(const float* __restrict__ SPK, float* __restrict__ ATTN)
{
  __shared__ float At[16][64];
  __shared__ float Bt[16][64];
  int bi = blockIdx.z, e = bi >> 5, tb = bi & 31;
  const float* A = SPK + (size_t)tb * ROWS * N + (size_t)(484 + e * ED) * N;   // q (96,256)
  const float* Bk = SPK + (size_t)tb * ROWS * N;                                // k (96,256)
  float* Ob = ATTN + (size_t)bi * N * N;
  int m0 = blockIdx.x * 64, n0 = blockIdx.y * 64;
  int t = threadIdx.x, tx = t & 15, ty = t >> 4;
  float acc[4][4] = {};
  for (int kt = 0; kt < ED; kt += 16) {
#pragma unroll
    for (int l = 0; l < 4; ++l) {
      int idx = t + l * 256;
      int r = idx >> 6, c = idx & 63;
      At[r][c] = A[(size_t)(kt + r) * N + n0 + c];
      Bt[r][c] = Bk[(size_t)(kt + r) * N + m0 + c];
    }
    __syncthreads();
#pragma unroll
    for (int k = 0; k < 16; ++k) {
      float a[4], b[4];
#pragma unroll
      for (int i = 0; i < 4; ++i) a[i] = At[k][ty * 4 + i];
#pragma unroll
      for (int j = 0; j < 4; ++j) b[j] = Bt[k][tx * 4 + j];
#pragma unroll
      for (int i = 0; i < 4; ++i)
#pragma unroll
        for (int j = 0; j < 4; ++j) acc[i][j] += a[i] * b[j];
    }
    __syncthreads();
  }
#pragma unroll
  for (int i = 0; i < 4; ++i)
#pragma unroll
    for (int j = 0; j < 4; ++j)
      Ob[(size_t)(n0 + ty * 4 + i) * N + m0 + tx * 4 + j] = acc[i][j];
}

// ---------------- res[e,tb,n,d] = sum_m attn[n,m]*v[d,m] ----------------
__global__ __launch_bounds__(256) void res_kernel(
    const float* __restrict__ ATTN, const float* __restrict__ SPK, float* __restrict__ RES)
{
  __shared__ float At[16][65];
  __shared__ float Bt[16][65];
  int bi = blockIdx.z, tb = bi & 31;
  const float* A = ATTN + (size_t)bi * N * N;                        // (256 n, 256 m)
  const float* Bv = SPK + (size_t)tb * ROWS * N + (size_t)ED * N;    // v (384 d, 256 m)
  float* Ob = RES + (size_t)bi * N * C;
  int d0 = blockIdx.x * 64, n0 = blockIdx.y * 64;
  int t = threadIdx.x, tx = t & 15, ty = t >> 4;
  float acc[4][4] = {};
  for (int kt = 0; kt < N; kt += 16) {
#pragma unroll
    for (int l = 0; l < 4; ++l) {
      int idx = t + l * 256;
      int r = idx >> 4, c = idx & 15;
      At[c][r] = A[(size_t)(n0 + r) * N + kt + c];
      Bt[c][r] = Bv[(size_t)(d0 + r) * N + kt + c];
    }
    __syncthreads();
#pragma unroll
    for (int k = 0; k < 16; ++k) {
      float a[4], b[4];
#pragma unroll
      for (int i = 0; i < 4; ++i) a[i] = At[k][ty * 4 + i];
#pragma unroll
      for (int j = 0; j < 4; ++j) b[j] = Bt[k][tx * 4 + j];
#pragma unroll
      for (int i = 0; i < 4; ++i)
#pragma unroll
        for (int j = 0; j < 4; ++j) acc[i][j] += a[i] * b[j];
    }
    __syncthreads();
  }
#pragma unroll
  for (int i = 0; i < 4; ++i)
#pragma unroll
    for (int j = 0; j < 4; ++j)
      Ob[(size_t)(n0 + ty * 4 + i) * C + d0 + tx * 4 + j] = acc[i][j];
}

// ---------------- y[tb,d,n] = sum_e w[tb,e,n]*res_spk[e,tb,n,d] ----------------
__global__ __launch_bounds__(1024) void y_kernel(
    const float* __restrict__ SPK, const float* __restrict__ RES, float* __restrict__ Y)
{
  __shared__ float tile[32][33];
  int tb = blockIdx.z;
  int d0 = blockIdx.y * 32, n0 = blockIdx.x * 32;
  int tx = threadIdx.x, ty = threadIdx.y;
  int n = n0 + ty, d = d0 + tx;
  const float* wrow = SPK + (size_t)tb * ROWS * N + 480 * N;
  float v = 0.0f;
#pragma unroll
  for (int e = 0; e < 4; ++e) {
    float w = wrow[e * N + n];
    float r = RES[((size_t)(e * TB + tb) * N + n) * C + d];
    v += w * r;
  }
  tile[ty][tx] = v;
  __syncthreads();
  Y[(size_t)tb * C * N + (size_t)(d0 + ty) * N + n0 + tx] = tile[tx][ty];
}

// ---------------- LIF(pp) + residual: out = x + spike ----------------
__global__ __launch_bounds__(256) void lif_addx(
    const float* __restrict__ pp, const float* __restrict__ xin, float* __restrict__ out)
{
  int j = blockIdx.x * 256 + threadIdx.x;
  int b = blockIdx.y;
  float mem = 0.0f;
#pragma unroll
  for (int t = 0; t < 4; ++t) {
    size_t idx = (size_t)(t * 8 + b) * (C * N) + j;
    float x = pp[idx];
    mem += (x - mem) * 0.5f;
    float sp = (mem >= 1.0f) ? 1.0f : 0.0f;
    out[idx] = xin[idx] + sp;
    mem = (sp != 0.0f) ? 0.0f : mem;
  }
}

// ---------------- depthwise 3x3 + BN + LIF + gate: M = lif(bn(conv(x1)))*x2 ----------------
__global__ __launch_bounds__(256) void dwconv_kernel(
    const float* __restrict__ H, const float* __restrict__ DW,
    const float* __restrict__ aS, const float* __restrict__ aB, float* __restrict__ M)
{
  int u = blockIdx.x * 256 + threadIdx.x;   // over 8*1024*256
  int n = u & 255;
  int ch = (u >> 8) & 1023;
  int b = u >> 18;
  int px = n & 15, py = n >> 4;
  float w[9];
#pragma unroll
  for (int i = 0; i < 9; ++i) w[i] = DW[ch * 9 + i];
  float s = aS[ch], bb = aB[ch];
  float mem = 0.0f;
#pragma unroll
  for (int t = 0; t < 4; ++t) {
    const float* hp = H + ((size_t)(t * 8 + b) * HID + ch) * N;
    float acc = 0.0f;
#pragma unroll
    for (int dy = 0; dy < 3; ++dy) {
      int yy = py + dy - 1;
      if (yy < 0 || yy > 15) continue;
#pragma unroll
      for (int dx = 0; dx < 3; ++dx) {
        int xx = px + dx - 1;
        if (xx < 0 || xx > 15) continue;
        acc += hp[yy * 16 + xx] * w[dy * 3 + dx];
      }
    }
    float z = acc * s + bb;
    mem += (z - mem) * 0.5f;
    float sp = (mem >= 1.0f) ? 1.0f : 0.0f;
    mem = (sp != 0.0f) ? 0.0f : mem;
    float x2 = H[((size_t)(t * 8 + b) * HID + HH + ch) * N + n];
    M[((size_t)(t * 8 + b) * HH + ch) * N + n] = sp * x2;
  }
}

// ---------------- final: out += lif(f2) ----------------
__global__ __launch_bounds__(256) void lif_accum(const float* __restrict__ f2, float* __restrict__ out)
{
  int j = blockIdx.x * 256 + threadIdx.x;
  int b = blockIdx.y;
  float mem = 0.0f;
#pragma unroll
  for (int t = 0; t < 4; ++t) {
    size_t idx = (size_t)(t * 8 + b) * (C * N) + j;
    float x = f2[idx];
    mem += (x - mem) * 0.5f;
    float sp = (mem >= 1.0f) ? 1.0f : 0.0f;
    out[idx] += sp;
    mem = (sp != 0.0f) ? 0.0f : mem;
  }
}

} // namespace

extern "C" void kernel_launch(void* const* d_in, const int* in_sizes, int n_in,
                              void* d_out, int out_size, void* d_ws, size_t ws_size,
                              hipStream_t stream)
{
  const float* x         = (const float*)d_in[0];
  const float* k_w       = (const float*)d_in[2];
  const float* v_w       = (const float*)d_in[3];
  const float* router_w  = (const float*)d_in[4];
  const float* router_b  = (const float*)d_in[5];
  const float* router_g  = (const float*)d_in[6];
  const float* router_be = (const float*)d_in[7];
  const float* exp_w     = (const float*)d_in[8];
  const float* exp_g     = (const float*)d_in[9];
  const float* exp_b     = (const float*)d_in[10];
  const float* proj_w    = (const float*)d_in[11];
  const float* proj_b    = (const float*)d_in[12];
  const float* proj_g    = (const float*)d_in[13];
  const float* proj_be   = (const float*)d_in[14];
  const float* fc1_w     = (const float*)d_in[15];
  const float* fc1_b     = (const float*)d_in[16];
  const float* fc1_g     = (const float*)d_in[17];
  const float* fc1_be    = (const float*)d_in[18];
  const float* dw_w      = (const float*)d_in[19];
  const float* dw_b      = (const float*)d_in[20];
  const float* dw_g      = (const float*)d_in[21];
  const float* dw_be     = (const float*)d_in[22];
  const float* fc2_w     = (const float*)d_in[23];
  const float* fc2_b     = (const float*)d_in[24];
  const float* fc2_g     = (const float*)d_in[25];
  const float* fc2_be    = (const float*)d_in[26];

  float* ws  = (float*)d_ws;
  float* out = (float*)d_out;
  dim3 blk(256);

  // weight pack + folded BN affines
  pack_kernel<<<1302, blk, 0, stream>>>(k_w, v_w, router_w, router_b, router_g, router_be,
                                        exp_w, exp_g, exp_b,
                                        ws + O_WPACK, ws + O_A1S, ws + O_A1B);
  aff_kernel<<<2, blk, 0, stream>>>(proj_g, proj_b, proj_be, ws + O_APS, ws + O_APB, 384);
  aff_kernel<<<8, blk, 0, stream>>>(fc1_g, fc1_b, fc1_be, ws + O_AHS, ws + O_AHB, 2048);
  aff_kernel<<<4, blk, 0, stream>>>(dw_g, dw_b, dw_be, ws + O_ADS, ws + O_ADB, 1024);
  aff_kernel<<<2, blk, 0, stream>>>(fc2_g, fc2_b, fc2_be, ws + O_AFS, ws + O_AFB, 384);

  // fused k/v/router/q projection GEMM (868 rows) + BN affine epilogue
  gemm_wx<<<dim3(4, 14, 32), blk, 0, stream>>>(ws + O_WPACK, x, ws + O_PRE,
                                               ws + O_A1S, ws + O_A1B,
                                               ROWS, C, (long)C * N, (long)ROWS * N);
  // LIF over all 868 feature rows (in place -> spikes)
  lif_kernel<<<dim3(ROWS, 8), blk, 0, stream>>>(ws + O_PRE, ROWS * N);

  // attn = q^T k  (exact small ints in fp32)
  attn_kernel<<<dim3(4, 4, 128), blk, 0, stream>>>(ws + O_PRE, ws + O_ATTN);
  // res = attn @ v^T (exact ints < 2^24)
  res_kernel<<<dim3(6, 4, 128), blk, 0, stream>>>(ws + O_ATTN, ws + O_PRE, ws + O_RES);
  // LIF on res (exact dynamics)
  lif_kernel<<<dim3(N * C / 256, 32), blk, 0, stream>>>(ws + O_RES, N * C);
  // router-weighted expert sum -> y (TB,C,N)
  y_kernel<<<dim3(8, 12, 32), dim3(32, 32), 0, stream>>>(ws + O_PRE, ws + O_RES, ws + O_Y);
  // proj GEMM + BN
  gemm_wx<<<dim3(4, 6, 32), blk, 0, stream>>>(proj_w, ws + O_Y, ws + O_PP,
                                              ws + O_APS, ws + O_APB,
                                              C, C, (long)C * N, (long)C * N);
  // x = x + lif(proj)
  lif_addx<<<dim3(384, 8), blk, 0, stream>>>(ws + O_PP, x, out);

  // fc1 GEMM + BN
  gemm_wx<<<dim3(4, 32, 32), blk, 0, stream>>>(fc1_w, out, ws + O_H,
                                               ws + O_AHS, ws + O_AHB,
                                               HID, C, (long)C * N, (long)HID * N);
  lif_kernel<<<dim3(HID * N / 256, 8), blk, 0, stream>>>(ws + O_H, HID * N);
  // depthwise conv + BN + LIF + gate
  dwconv_kernel<<<dim3(8 * HH * N / 256), blk, 0, stream>>>(ws + O_H, dw_w,
                                                            ws + O_ADS, ws + O_ADB, ws + O_M);
  // fc2 GEMM + BN
  gemm_wx<<<dim3(4, 6, 32), blk, 0, stream>>>(fc2_w, ws + O_M, ws + O_F2,
                                              ws + O_AFS, ws + O_AFB,
                                              C, HH, (long)HH * N, (long)C * N);
  // out += lif(fc2)
  lif_accum<<<dim3(384, 8), blk, 0, stream>>>(ws + O_F2, out);
}